// Round 6
// baseline (648.498 us; speedup 1.0000x reference)
//
#include <hip/hip_runtime.h>

// Stability of stochastic-computing bit streams.
// Per stream n: cnt_t = cumsum(bits), pp = cnt/t*2-1, pe = pp - clip(src,-1,1),
// cts = last t with |pe| > 0.05, stability = 1 - clamp(cts,1,T)/T.
//
// R5b: NT + full-width variant (R5 failed to compile: __builtin_nontemporal_load
// rejects HIP_vector_type; use a native clang ext_vector int4 instead).
// History: R1 717 (f32-div VALU storm), R2 672 (f64-rcp), R3 677 (max-occupancy
// null -> occupancy irrelevant), R4 648 (NT dwordx2: -29 us, real -> L2/L3
// victim alloc was costing). Bench dur includes ~510-590 us of harness
// poison/restore (the 2 GiB ws fill alone is 340 us in every profile; our
// kernel never appears in top-5), so kernel-side is ~60-140 us vs the 81-86 us
// floor (bits = 512 MiB read-once). This round: NT dwordx4 loads (1 KiB/wave/
// instr, 4x fewer VMEM issues than R4). If delta <= ~5 us -> ROOFLINE.
//
// Bit-exactness without f32 division: for c in [0,256], t in [1,256], c/t in
// lowest terms has denominator <= 2^8, so it is never an f32 rounding midpoint
// (those need denominators >= 2^24); distance to any midpoint >= ~2^-33
// relative, while (double)c * RN64(1/t) carries error <= 2^-52. Hence
//   (float)((double)c * rcp64[t])  ==  (float)c / (float)t   bit-for-bit.
// fmaf(q,2,-1) == RN(2q-1) matches ref's (q*2)-1 since 2q is exact.

#define THR 0.05f

typedef int vint4 __attribute__((ext_vector_type(4)));   // native clang vector:
// accepted by __builtin_nontemporal_load, lowers to global_load_dwordx4 ... nt

__global__ __launch_bounds__(256, 4) void stability_kernel(
    const float4* __restrict__ src4,
    const vint4* __restrict__ bits4,   // [T][n4], four bit-streams per 16B
    float4* __restrict__ out4,
    int n4, int T)
{
    __shared__ double rcp[256];        // rcp[t-1] = RN64(1/t), wave-uniform reads
    for (int u = threadIdx.x; u < T; u += 256)
        rcp[u] = 1.0 / (double)(u + 1);
    __syncthreads();

    int i = blockIdx.x * 256 + threadIdx.x;
    if (i >= n4) return;

    float4 s = src4[i];
    float s0 = fminf(fmaxf(s.x, -1.0f), 1.0f);
    float s1 = fminf(fmaxf(s.y, -1.0f), 1.0f);
    float s2 = fminf(fmaxf(s.z, -1.0f), 1.0f);
    float s3 = fminf(fmaxf(s.w, -1.0f), 1.0f);

    int c0 = 0, c1 = 0, c2 = 0, c3 = 0;   // running one-counts
    int l0 = 0, l1 = 0, l2 = 0, l3 = 0;   // last unstable cycle (0 = never)

    const vint4* p = bits4 + i;
    #pragma unroll 8
    for (int t = 0; t < T; ++t) {
        vint4 b = __builtin_nontemporal_load(p);   // global_load_dwordx4 ... nt
        p += n4;
        c0 += b.x; c1 += b.y; c2 += b.z; c3 += b.w;
        double r = rcp[t];
        float q0 = (float)((double)c0 * r);   // == (float)c0/(float)(t+1), exact
        float q1 = (float)((double)c1 * r);
        float q2 = (float)((double)c2 * r);
        float q3 = (float)((double)c3 * r);
        float pe0 = fmaf(q0, 2.0f, -1.0f) - s0;
        float pe1 = fmaf(q1, 2.0f, -1.0f) - s1;
        float pe2 = fmaf(q2, 2.0f, -1.0f) - s2;
        float pe3 = fmaf(q3, 2.0f, -1.0f) - s3;
        if (fabsf(pe0) > THR) l0 = t + 1;
        if (fabsf(pe1) > THR) l1 = t + 1;
        if (fabsf(pe2) > THR) l2 = t + 1;
        if (fabsf(pe3) > THR) l3 = t + 1;
    }

    float Tf = (float)T;
    float4 o;
    o.x = 1.0f - (float)min(max(l0, 1), T) / Tf;
    o.y = 1.0f - (float)min(max(l1, 1), T) / Tf;
    o.z = 1.0f - (float)min(max(l2, 1), T) / Tf;
    o.w = 1.0f - (float)min(max(l3, 1), T) / Tf;
    out4[i] = o;
}

extern "C" void kernel_launch(void* const* d_in, const int* in_sizes, int n_in,
                              void* d_out, int out_size, void* d_ws, size_t ws_size,
                              hipStream_t stream) {
    const float* source = (const float*)d_in[0];
    const int*   bits   = (const int*)d_in[1];
    float*       out    = (float*)d_out;

    int n  = in_sizes[0];          // 524288 streams
    int T  = in_sizes[1] / n;      // 256 cycles
    int n4 = n / 4;                // 4 streams per thread

    const int block = 256;
    int grid = (n4 + block - 1) / block;   // 512 blocks

    stability_kernel<<<grid, block, 0, stream>>>(
        (const float4*)source, (const vint4*)bits, (float4*)out, n4, T);
}